// Round 10
// baseline (2562.817 us; speedup 1.0000x reference)
//
#include <hip/hip_runtime.h>

// RNNSequenceEncoder: B=256, T=256, IN=128, H=1024
// Round-10: AMORTIZE the R4 protocol (measured-best, 1257us) instead of
// redesigning it (R5-R9 all regressed). The 16 row-blocks are independent
// recurrence chains -> each WG now advances TWO row-blocks (p and p+8) per
// iteration in lockstep. All CP legs (poll, stage, store-ack, flag) are
// shared between the two blocks, so per-step sync cost halves. Protocol
// semantics are byte-for-byte R4: sc0sc1 everywhere, 2-deep buffers, 8
// pollers/WG (R9 lesson: many pollers flood the CP), merged per-WG flag,
// 3 barriers/iter. wrec is column-indexed -> shared across blocks (no extra
// weight registers). 64 WGs x 512 threads, 64KB LDS (two 16x1024 bf16 tiles).

#define Bdim 256
#define Tdim 256
#define INdim 128
#define Hdim 1024

typedef __attribute__((ext_vector_type(8))) __bf16 bf16x8;
typedef __attribute__((ext_vector_type(4))) float f32x4;
typedef __attribute__((ext_vector_type(4))) int i32x4;

#define OUT_BYTES ((size_t)Bdim * Tdim * Hdim * 4)   /* 256 MB */
#define SBYTES ((size_t)Bdim * Hdim * 2)             /* one bf16 state buffer: 512 KB */
#define CNT_BYTES 32768
#define SCRATCH_BYTES (CNT_BYTES + 2 * SBYTES)

// --- device-coherent ops (bypass L1+L2; visible device-wide; PROVEN) ---
static __device__ __forceinline__ void st_b16_c(void* p, unsigned v) {
  asm volatile("global_store_short %0, %1, off sc0 sc1" :: "v"(p), "v"(v) : "memory");
}
static __device__ __forceinline__ void st_b32_c(void* p, unsigned v) {
  asm volatile("global_store_dword %0, %1, off sc0 sc1" :: "v"(p), "v"(v) : "memory");
}
static __device__ __forceinline__ unsigned ld_b32_c(const void* p) {
  unsigned v;
  asm volatile("global_load_dword %0, %1, off sc0 sc1\n\ts_waitcnt vmcnt(0)"
               : "=v"(v) : "v"(p) : "memory");
  return v;
}
static __device__ __forceinline__ i32x4 ld_b128_c(const void* p) {
  i32x4 v;
  asm volatile("global_load_dwordx4 %0, %1, off sc0 sc1" : "=v"(v) : "v"(p) : "memory");
  return v;
}
static __device__ __forceinline__ void wait_vm0() {
  asm volatile("s_waitcnt vmcnt(0)" ::: "memory");
}

static __device__ __forceinline__ bf16x8 cvt8(f32x4 lo, f32x4 hi) {
  bf16x8 r;
  r[0] = (__bf16)lo[0]; r[1] = (__bf16)lo[1]; r[2] = (__bf16)lo[2]; r[3] = (__bf16)lo[3];
  r[4] = (__bf16)hi[0]; r[5] = (__bf16)hi[1]; r[6] = (__bf16)hi[2]; r[7] = (__bf16)hi[3];
  return r;
}
static __device__ __forceinline__ unsigned short bfbits(float f) {
  __bf16 b = (__bf16)f;
  return __builtin_bit_cast(unsigned short, b);
}

// state fragment from an LDS tile: lane holds rows[lane&15][k0..k0+7],
// k0 = kk*32 + (lane>>4)*8, through the XOR swizzle (16B chunk ch at
// ch ^ (row&7)). A/B use identical K-packing so HW K-permutation cancels.
static __device__ __forceinline__ bf16x8 afrag(const __bf16* sT, int lane, int kk) {
  int row = lane & 15;
  int chq = kk * 4 + (lane >> 4);
  return *(const bf16x8*)(sT + (size_t)row * Hdim + ((chq ^ (row & 7)) << 3));
}

__global__ void zero_cnt(i32x4* p) {
  p[(size_t)blockIdx.x * 256 + threadIdx.x] = (i32x4){0, 0, 0, 0};
}

__global__ void __launch_bounds__(512, 1)
rnn_fused(const float* __restrict__ x, const float* __restrict__ W_in,
          const float* __restrict__ b_in, const float* __restrict__ W_rec,
          const float* __restrict__ b_rec, const float* __restrict__ W_out,
          const float* __restrict__ b_out, float* __restrict__ out,
          char* __restrict__ scratch) {
  __shared__ __align__(16) __bf16 sA[2 * 16 * Hdim];  // two tiles, 64 KB
  __bf16* tA = sA;
  __bf16* tB = sA + 16 * Hdim;

  unsigned* counters = (unsigned*)scratch;
  __bf16* buf0 = (__bf16*)(scratch + CNT_BYTES);
  __bf16* buf1 = buf0 + (size_t)Bdim * Hdim;

  int wg = blockIdx.x;               // 0..63
  int p = wg & 7;                    // block pair id: row-blocks p and p+8
  int c = wg >> 3;                   // col chunk 0..7 (128 H cols)
  int rA = p, rB = p + 8;
  int tid = threadIdx.x;
  int lane = tid & 63;
  int ww = tid >> 6;                 // wave 0..7
  int kgrp = lane >> 4;

  int col = c * 128 + ww * 16 + (lane & 15);  // H column owned by this lane
  int xrowA = 16 * rA + (lane & 15);
  int xrowB = 16 * rB + (lane & 15);

  // flags: pair p's 8 per-WG flags at counters[(p*8+i)*32], 128B apart.
  // One flag covers BOTH blocks (published after both stores ack'd).
  unsigned* rbf = counters + (size_t)p * 8 * 32;
  unsigned* myflag = rbf + (size_t)c * 32;
  unsigned* gflags = counters + 4096;          // 64 epilogue one-shot flags

  // stage mapping (per tile): thread handles chunks slot=k*512+tid, k=0..3;
  // row = slot>>7, ch = slot&127; LDS chunk at (ch ^ (row&7)).
  int s0r = (tid + 0) >> 7, s0c = (tid + 0) & 127;
  int s1r = (tid + 512) >> 7, s1c = (tid + 512) & 127;
  int s2r = (tid + 1024) >> 7, s2c = (tid + 1024) & 127;
  int s3r = (tid + 1536) >> 7, s3c = (tid + 1536) & 127;
  size_t g0 = (size_t)s0r * Hdim + s0c * 8, l0 = (size_t)s0r * Hdim + ((s0c ^ (s0r & 7)) << 3);
  size_t g1 = (size_t)s1r * Hdim + s1c * 8, l1 = (size_t)s1r * Hdim + ((s1c ^ (s1r & 7)) << 3);
  size_t g2 = (size_t)s2r * Hdim + s2c * 8, l2 = (size_t)s2r * Hdim + ((s2c ^ (s2r & 7)) << 3);
  size_t g3 = (size_t)s3r * Hdim + s3c * 8, l3 = (size_t)s3r * Hdim + ((s3c ^ (s3r & 7)) << 3);

  // --- preload weights (normal cached loads; shared by both blocks) ---
  bf16x8 wrec[32];  // W_rec row `col`, K=1024 -> 128 VGPRs
#pragma unroll
  for (int kk = 0; kk < 32; ++kk) {
    const float* q = W_rec + (size_t)col * Hdim + kk * 32 + kgrp * 8;
    wrec[kk] = cvt8(*(const f32x4*)q, *(const f32x4*)(q + 4));
  }
  bf16x8 win[4];    // W_in row `col`, K=128
#pragma unroll
  for (int kk = 0; kk < 4; ++kk) {
    const float* q = W_in + (size_t)col * INdim + kk * 32 + kgrp * 8;
    win[kk] = cvt8(*(const f32x4*)q, *(const f32x4*)(q + 4));
  }
  float b_rec_l = b_rec[col];
  float b_in_l = b_in[col];
  int xk0 = kgrp * 8;

  // --- phase 0: buf0 = v1 = ext_0 for both blocks ---
  {
    f32x4 eA = {0.f, 0.f, 0.f, 0.f}, eB = eA;
#pragma unroll
    for (int kk = 0; kk < 4; ++kk) {
      const float* qa = x + ((size_t)xrowA * Tdim + 0) * INdim + kk * 32 + xk0;
      const float* qb = x + ((size_t)xrowB * Tdim + 0) * INdim + kk * 32 + xk0;
      eA = __builtin_amdgcn_mfma_f32_16x16x32_bf16(
          cvt8(*(const f32x4*)qa, *(const f32x4*)(qa + 4)), win[kk], eA, 0, 0, 0);
      eB = __builtin_amdgcn_mfma_f32_16x16x32_bf16(
          cvt8(*(const f32x4*)qb, *(const f32x4*)(qb + 4)), win[kk], eB, 0, 0, 0);
    }
#pragma unroll
    for (int j = 0; j < 4; ++j) {
      st_b16_c(buf0 + (size_t)(16 * rA + kgrp * 4 + j) * Hdim + col, bfbits(eA[j] + b_in_l));
      st_b16_c(buf0 + (size_t)(16 * rB + kgrp * 4 + j) * Hdim + col, bfbits(eB[j] + b_in_l));
    }
  }
  wait_vm0();
  __syncthreads();
  if (tid == 0) st_b32_c(myflag, 1u);
  if (tid < 8) {
    unsigned* f = rbf + tid * 32;
    while (ld_b32_c(f) < 1u) __builtin_amdgcn_s_sleep(1);
  }
  __syncthreads();

  // --- scan: 256 steps; v(t+1) in buf[t&1] ---
  const __bf16* cur = buf0;
  __bf16* nxt = buf1;
  for (int t = 0; t < Tdim; ++t) {
    // issue stage loads for BOTH tiles back-to-back (one latency window)
    const __bf16* sgA = cur + (size_t)rA * 16 * Hdim;
    const __bf16* sgB = cur + (size_t)rB * 16 * Hdim;
    i32x4 dA0 = ld_b128_c(sgA + g0), dA1 = ld_b128_c(sgA + g1);
    i32x4 dA2 = ld_b128_c(sgA + g2), dA3 = ld_b128_c(sgA + g3);
    i32x4 dB0 = ld_b128_c(sgB + g0), dB1 = ld_b128_c(sgB + g1);
    i32x4 dB2 = ld_b128_c(sgB + g2), dB3 = ld_b128_c(sgB + g3);
    // x-prefetch t+1 (cached loads, convert to bf16 to save VGPRs)
    bf16x8 xfA[4], xfB[4];
    if (t + 1 < Tdim) {
#pragma unroll
      for (int kk = 0; kk < 4; ++kk) {
        const float* qa = x + ((size_t)xrowA * Tdim + (t + 1)) * INdim + kk * 32 + xk0;
        const float* qb = x + ((size_t)xrowB * Tdim + (t + 1)) * INdim + kk * 32 + xk0;
        xfA[kk] = cvt8(*(const f32x4*)qa, *(const f32x4*)(qa + 4));
        xfB[kk] = cvt8(*(const f32x4*)qb, *(const f32x4*)(qb + 4));
      }
    }
    wait_vm0();
    *(i32x4*)(tA + l0) = dA0; *(i32x4*)(tA + l1) = dA1;
    *(i32x4*)(tA + l2) = dA2; *(i32x4*)(tA + l3) = dA3;
    *(i32x4*)(tB + l0) = dB0; *(i32x4*)(tB + l1) = dB1;
    *(i32x4*)(tB + l2) = dB2; *(i32x4*)(tB + l3) = dB3;
    __syncthreads();  // both tiles complete
    f32x4 aA0 = {0.f, 0.f, 0.f, 0.f}, aA1 = aA0, aB0 = aA0, aB1 = aA0;
#pragma unroll
    for (int kk = 0; kk < 32; kk += 2) {
      aA0 = __builtin_amdgcn_mfma_f32_16x16x32_bf16(afrag(tA, lane, kk + 0), wrec[kk + 0], aA0, 0, 0, 0);
      aA1 = __builtin_amdgcn_mfma_f32_16x16x32_bf16(afrag(tA, lane, kk + 1), wrec[kk + 1], aA1, 0, 0, 0);
      aB0 = __builtin_amdgcn_mfma_f32_16x16x32_bf16(afrag(tB, lane, kk + 0), wrec[kk + 0], aB0, 0, 0, 0);
      aB1 = __builtin_amdgcn_mfma_f32_16x16x32_bf16(afrag(tB, lane, kk + 1), wrec[kk + 1], aB1, 0, 0, 0);
    }
    f32x4 accA = aA0 + aA1, accB = aB0 + aB1;
    f32x4 eA = {0.f, 0.f, 0.f, 0.f}, eB = eA;
    if (t + 1 < Tdim) {
#pragma unroll
      for (int kk = 0; kk < 4; ++kk) {
        eA = __builtin_amdgcn_mfma_f32_16x16x32_bf16(xfA[kk], win[kk], eA, 0, 0, 0);
        eB = __builtin_amdgcn_mfma_f32_16x16x32_bf16(xfB[kk], win[kk], eB, 0, 0, 0);
      }
    }
    // v(t+2) = relu(acc+b_rec) [+ ext_{t+1}]; C/D: col=lane&15, row=kgrp*4+j
#pragma unroll
    for (int j = 0; j < 4; ++j) {
      float sa = accA[j] + b_rec_l, sb = accB[j] + b_rec_l;
      sa = sa > 0.f ? sa : 0.f; sb = sb > 0.f ? sb : 0.f;
      if (t + 1 < Tdim) {
        sa += eA[j] + b_in_l; sb += eB[j] + b_in_l;
      }
      st_b16_c(nxt + (size_t)(16 * rA + kgrp * 4 + j) * Hdim + col, bfbits(sa));
      st_b16_c(nxt + (size_t)(16 * rB + kgrp * 4 + j) * Hdim + col, bfbits(sb));
    }
    // publish v(t+2) (both blocks) -> poll peers (R4 semantics, merged flag)
    unsigned tgt = (unsigned)(t + 2);
    wait_vm0();
    __syncthreads();
    if (tid == 0) st_b32_c(myflag, tgt);
    if (tid < 8) {
      unsigned* f = rbf + tid * 32;
      while (ld_b32_c(f) < tgt) __builtin_amdgcn_s_sleep(1);
    }
    __syncthreads();
    const __bf16* tmp = cur; cur = nxt; nxt = (__bf16*)tmp;
  }

  // --- epilogue: stage v257 (in buf0 == cur), grid barrier, W_out, bcast ---
  {
    const __bf16* sgA = cur + (size_t)rA * 16 * Hdim;
    const __bf16* sgB = cur + (size_t)rB * 16 * Hdim;
    i32x4 dA0 = ld_b128_c(sgA + g0), dA1 = ld_b128_c(sgA + g1);
    i32x4 dA2 = ld_b128_c(sgA + g2), dA3 = ld_b128_c(sgA + g3);
    i32x4 dB0 = ld_b128_c(sgB + g0), dB1 = ld_b128_c(sgB + g1);
    i32x4 dB2 = ld_b128_c(sgB + g2), dB3 = ld_b128_c(sgB + g3);
    wait_vm0();
    *(i32x4*)(tA + l0) = dA0; *(i32x4*)(tA + l1) = dA1;
    *(i32x4*)(tA + l2) = dA2; *(i32x4*)(tA + l3) = dA3;
    *(i32x4*)(tB + l0) = dB0; *(i32x4*)(tB + l1) = dB1;
    *(i32x4*)(tB + l2) = dB2; *(i32x4*)(tB + l3) = dB3;
    __syncthreads();
  }
  // one-shot grid barrier (tail-scratch safety; proven protocol; 64 WGs)
  if (tid == 0) st_b32_c(gflags + (size_t)wg * 16, 1u);
  if (tid < 64) {
    unsigned* f = gflags + (size_t)tid * 16;
    while (ld_b32_c(f) < 1u) __builtin_amdgcn_s_sleep(1);
  }
  __syncthreads();

  f32x4 aA = {0.f, 0.f, 0.f, 0.f}, aB = aA;
#pragma unroll
  for (int kk = 0; kk < 32; ++kk) {
    const float* q = W_out + (size_t)col * Hdim + kk * 32 + kgrp * 8;
    bf16x8 wo = cvt8(*(const f32x4*)q, *(const f32x4*)(q + 4));
    aA = __builtin_amdgcn_mfma_f32_16x16x32_bf16(afrag(tA, lane, kk), wo, aA, 0, 0, 0);
    aB = __builtin_amdgcn_mfma_f32_16x16x32_bf16(afrag(tB, lane, kk), wo, aB, 0, 0, 0);
  }
  float bo = b_out[col];
  __syncthreads();  // all afrag reads done before LDS reuse
  float* sPA = (float*)tA;  // 16 x 128 plop tiles (f32, 8KB each)
  float* sPB = (float*)tB;
#pragma unroll
  for (int j = 0; j < 4; ++j) {
    sPA[(kgrp * 4 + j) * 128 + ww * 16 + (lane & 15)] = aA[j] + bo;
    sPB[(kgrp * 4 + j) * 128 + ww * 16 + (lane & 15)] = aB[j] + bo;
  }
  __syncthreads();

  int h32 = tid & 31, tloc = tid >> 5;
  for (int b = 0; b < 16; ++b) {
    f32x4 vA = *(const f32x4*)(sPA + b * 128 + h32 * 4);
    f32x4 vB = *(const f32x4*)(sPB + b * 128 + h32 * 4);
#pragma unroll
    for (int tb = 0; tb < 16; ++tb) {
      int t = tb * 16 + tloc;
      *(f32x4*)(out + ((size_t)(16 * rA + b) * Tdim + t) * Hdim + 128 * c + h32 * 4) = vA;
      *(f32x4*)(out + ((size_t)(16 * rB + b) * Tdim + t) * Hdim + 128 * c + h32 * 4) = vB;
    }
  }
}

extern "C" void kernel_launch(void* const* d_in, const int* in_sizes, int n_in,
                              void* d_out, int out_size, void* d_ws, size_t ws_size,
                              hipStream_t stream) {
  const float* x = (const float*)d_in[0];
  const float* W_in = (const float*)d_in[1];
  const float* b_in = (const float*)d_in[2];
  const float* W_rec = (const float*)d_in[3];
  const float* b_rec = (const float*)d_in[4];
  const float* W_out = (const float*)d_in[5];
  const float* b_out = (const float*)d_in[6];
  float* out = (float*)d_out;
  (void)in_sizes; (void)n_in; (void)out_size;

  char* scratch = (ws_size >= SCRATCH_BYTES)
                      ? (char*)d_ws
                      : ((char*)d_out + OUT_BYTES - SCRATCH_BYTES);

  zero_cnt<<<dim3(CNT_BYTES / 4096), dim3(256), 0, stream>>>((i32x4*)scratch);
  rnn_fused<<<dim3(64), dim3(512), 0, stream>>>(x, W_in, b_in, W_rec, b_rec,
                                                W_out, b_out, out, scratch);
}

// Round 11
// 1571.696 us; speedup vs baseline: 1.6306x; 1.6306x over previous
//
#include <hip/hip_runtime.h>

// RNNSequenceEncoder: B=256, T=256, IN=128, H=1024
// Round-11 = R4 (proven best, 1257us) + two volume/pipeline deltas:
//  (1) self-slice staging: own 128-col slice goes registers->LDS (R9-proven
//      mechanism), cutting per-WG CP stage volume 32KB -> 28KB. R10 showed
//      per-step time scales with per-CU CP volume, so this is the lever.
//  (2) wave-specialized stage: consumer wave w polls ONLY producer-WG w's
//      flag (lane-0 scalar poll; 8 pollers/WG as in R4 - no R9 poll flood),
//      then immediately loads that 4KB slice - poll RTT pipelines with
//      transfer. Collective safety unchanged: barrier joins all waves before
//      MFMA/stores, so all 8 "peer >= t+1" checks are established before
//      v(t) is overwritten. Producer side byte-identical to R4 (one per-WG
//      flag, published after vmcnt0 + full barrier).
// Everything else (sc0sc1 ops, 2-deep buffers, MFMA loop, epilogue) = R4.

#define Bdim 256
#define Tdim 256
#define INdim 128
#define Hdim 1024

typedef __attribute__((ext_vector_type(8))) __bf16 bf16x8;
typedef __attribute__((ext_vector_type(4))) float f32x4;
typedef __attribute__((ext_vector_type(4))) int i32x4;

#define OUT_BYTES ((size_t)Bdim * Tdim * Hdim * 4)   /* 256 MB */
#define SBYTES ((size_t)Bdim * Hdim * 2)             /* one bf16 state buffer: 512 KB */
#define CNT_BYTES 32768
#define SCRATCH_BYTES (CNT_BYTES + 2 * SBYTES)

// --- device-coherent ops (bypass L1+L2; visible device-wide; PROVEN) ---
static __device__ __forceinline__ void st_b16_c(void* p, unsigned v) {
  asm volatile("global_store_short %0, %1, off sc0 sc1" :: "v"(p), "v"(v) : "memory");
}
static __device__ __forceinline__ void st_b32_c(void* p, unsigned v) {
  asm volatile("global_store_dword %0, %1, off sc0 sc1" :: "v"(p), "v"(v) : "memory");
}
static __device__ __forceinline__ unsigned ld_b32_c(const void* p) {
  unsigned v;
  asm volatile("global_load_dword %0, %1, off sc0 sc1\n\ts_waitcnt vmcnt(0)"
               : "=v"(v) : "v"(p) : "memory");
  return v;
}
static __device__ __forceinline__ i32x4 ld_b128_c(const void* p) {
  i32x4 v;
  asm volatile("global_load_dwordx4 %0, %1, off sc0 sc1" : "=v"(v) : "v"(p) : "memory");
  return v;
}
static __device__ __forceinline__ void wait_vm0() {
  asm volatile("s_waitcnt vmcnt(0)" ::: "memory");
}

static __device__ __forceinline__ bf16x8 cvt8(f32x4 lo, f32x4 hi) {
  bf16x8 r;
  r[0] = (__bf16)lo[0]; r[1] = (__bf16)lo[1]; r[2] = (__bf16)lo[2]; r[3] = (__bf16)lo[3];
  r[4] = (__bf16)hi[0]; r[5] = (__bf16)hi[1]; r[6] = (__bf16)hi[2]; r[7] = (__bf16)hi[3];
  return r;
}
static __device__ __forceinline__ unsigned short bfbits(float f) {
  __bf16 b = (__bf16)f;
  return __builtin_bit_cast(unsigned short, b);
}

// state fragment from LDS: lane holds rows[lane&15][k0..k0+7], k0=kk*32+(lane>>4)*8,
// through the XOR swizzle (16B chunk ch at ch ^ (row&7)). A/B use identical
// K-packing so any HW K-permutation cancels. (Proven rounds 2-10.)
static __device__ __forceinline__ bf16x8 afrag(const __bf16* sA, int lane, int kk) {
  int row = lane & 15;
  int chq = kk * 4 + (lane >> 4);
  return *(const bf16x8*)(sA + (size_t)row * Hdim + ((chq ^ (row & 7)) << 3));
}

__global__ void zero_cnt(unsigned* c) { c[blockIdx.x * 256 + threadIdx.x] = 0u; }

__global__ void __launch_bounds__(512, 1)
rnn_fused(const float* __restrict__ x, const float* __restrict__ W_in,
          const float* __restrict__ b_in, const float* __restrict__ W_rec,
          const float* __restrict__ b_rec, const float* __restrict__ W_out,
          const float* __restrict__ b_out, float* __restrict__ out,
          char* __restrict__ scratch) {
  __shared__ __align__(16) __bf16 sA[16 * Hdim];  // 32 KB

  unsigned* counters = (unsigned*)scratch;
  __bf16* buf0 = (__bf16*)(scratch + CNT_BYTES);
  __bf16* buf1 = buf0 + (size_t)Bdim * Hdim;

  int wg = blockIdx.x;               // 0..127
  int idx = wg >> 3;
  int r = (wg & 7) + 8 * (idx & 1);  // row block 0..15; its 8 WGs share wg&7
  int c = idx >> 1;                  // col chunk 0..7 (128 H cols)
  int tid = threadIdx.x;
  int lane = tid & 63;
  int ww = tid >> 6;                 // wave 0..7
  int kgrp = lane >> 4;

  int col = c * 128 + ww * 16 + (lane & 15);  // H column owned by this lane
  int xrow = 16 * r + (lane & 15);            // batch row for x A-fragments

  unsigned* rbf = counters + (size_t)r * 8 * 32;   // row-block flags, 128B apart
  unsigned* myflag = rbf + (size_t)c * 32;
  unsigned* gflags = counters + 4096;              // epilogue one-shot flags

  // wave-specialized stage: wave ww stages producer WG ww's 128-col slice
  // (unless ww == c -> self, supplied from registers by ALL waves).
  bool rem = (ww != c);
  unsigned* wflag = rbf + (size_t)ww * 32;     // producer WG ww's flag
  int chs = ww * 16 + (lane & 15);             // 8-bf16 col chunk in slice ww
  int rbase = lane >> 4;                       // rows rbase, +4, +8, +12
  size_t gs0 = (size_t)(rbase + 0) * Hdim + chs * 8;
  size_t gs1 = (size_t)(rbase + 4) * Hdim + chs * 8;
  size_t gs2 = (size_t)(rbase + 8) * Hdim + chs * 8;
  size_t gs3 = (size_t)(rbase + 12) * Hdim + chs * 8;
  size_t lsA = (size_t)(rbase + 0) * Hdim + ((chs ^ rbase) << 3);
  size_t lsB = (size_t)(rbase + 4) * Hdim + ((chs ^ (rbase + 4)) << 3);
  size_t lsC = (size_t)(rbase + 8) * Hdim + ((chs ^ rbase) << 3);
  size_t lsD = (size_t)(rbase + 12) * Hdim + ((chs ^ (rbase + 4)) << 3);

  // self-write LDS addresses: lane's 4 values live at (row=kgrp*4+j, col)
  unsigned short* sAu = (unsigned short*)sA;
  int colch = col >> 3, coloff = col & 7;
#define SELF_ADDR(j) ((size_t)(kgrp * 4 + (j)) * Hdim + \
                      (((colch ^ ((kgrp * 4 + (j)) & 7)) << 3) + coloff))

  // --- preload weights (normal cached loads) ---
  bf16x8 wrec[32];  // W_rec row `col`, K=1024 -> 128 VGPRs
#pragma unroll
  for (int kk = 0; kk < 32; ++kk) {
    const float* p = W_rec + (size_t)col * Hdim + kk * 32 + kgrp * 8;
    wrec[kk] = cvt8(*(const f32x4*)p, *(const f32x4*)(p + 4));
  }
  bf16x8 win[4];    // W_in row `col`, K=128
#pragma unroll
  for (int kk = 0; kk < 4; ++kk) {
    const float* p = W_in + (size_t)col * INdim + kk * 32 + kgrp * 8;
    win[kk] = cvt8(*(const f32x4*)p, *(const f32x4*)(p + 4));
  }
  float b_rec_l = b_rec[col];
  float b_in_l = b_in[col];
  int xk0 = kgrp * 8;

  // --- phase 0: v1 = ext_0 -> buf0 (coherent stores) + sv registers ---
  unsigned short sv0, sv1, sv2, sv3;
  {
    f32x4 e = {0.f, 0.f, 0.f, 0.f};
#pragma unroll
    for (int kk = 0; kk < 4; ++kk) {
      const float* p = x + ((size_t)xrow * Tdim + 0) * INdim + kk * 32 + xk0;
      e = __builtin_amdgcn_mfma_f32_16x16x32_bf16(
          cvt8(*(const f32x4*)p, *(const f32x4*)(p + 4)), win[kk], e, 0, 0, 0);
    }
    sv0 = bfbits(e[0] + b_in_l); sv1 = bfbits(e[1] + b_in_l);
    sv2 = bfbits(e[2] + b_in_l); sv3 = bfbits(e[3] + b_in_l);
    st_b16_c(buf0 + (size_t)(16 * r + kgrp * 4 + 0) * Hdim + col, sv0);
    st_b16_c(buf0 + (size_t)(16 * r + kgrp * 4 + 1) * Hdim + col, sv1);
    st_b16_c(buf0 + (size_t)(16 * r + kgrp * 4 + 2) * Hdim + col, sv2);
    st_b16_c(buf0 + (size_t)(16 * r + kgrp * 4 + 3) * Hdim + col, sv3);
  }
  wait_vm0();
  __syncthreads();
  if (tid == 0) st_b32_c(myflag, 1u);   // publish v1

  // --- scan: iter t stages v(t+1) from cur, stores v(t+2) to nxt ---
  const __bf16* cur = buf0;
  __bf16* nxt = buf1;
  for (int t = 0; t < Tdim; ++t) {
    __syncthreads();  // A: all waves done MFMA-reading the previous tile
    // per-wave: poll my producer's flag, then load its 4KB slice
    i32x4 d0, d1, d2, d3;
    if (rem) {
      if (lane == 0) {
        unsigned need = (unsigned)(t + 1);
        while (ld_b32_c(wflag) < need) __builtin_amdgcn_s_sleep(1);
      }
      const __bf16* src = cur + (size_t)r * 16 * Hdim;
      d0 = ld_b128_c(src + gs0);
      d1 = ld_b128_c(src + gs1);
      d2 = ld_b128_c(src + gs2);
      d3 = ld_b128_c(src + gs3);
    }
    // x-prefetch (cached) hides under the CP transfer
    f32x4 xlo[4], xhi[4];
    if (t + 1 < Tdim) {
#pragma unroll
      for (int kk = 0; kk < 4; ++kk) {
        const float* p = x + ((size_t)xrow * Tdim + (t + 1)) * INdim + kk * 32 + xk0;
        xlo[kk] = *(const f32x4*)p;
        xhi[kk] = *(const f32x4*)(p + 4);
      }
    }
    wait_vm0();
    if (rem) {
      *(i32x4*)(sA + lsA) = d0;
      *(i32x4*)(sA + lsB) = d1;
      *(i32x4*)(sA + lsC) = d2;
      *(i32x4*)(sA + lsD) = d3;
    }
    // self slice from registers (all waves contribute their own 4 values)
    sAu[SELF_ADDR(0)] = sv0; sAu[SELF_ADDR(1)] = sv1;
    sAu[SELF_ADDR(2)] = sv2; sAu[SELF_ADDR(3)] = sv3;
    __syncthreads();  // B: tile complete; also joins all 8 peer checks
    f32x4 a0 = {0.f, 0.f, 0.f, 0.f}, a1 = a0, a2 = a0, a3 = a0;
#pragma unroll
    for (int kk = 0; kk < 32; kk += 4) {
      a0 = __builtin_amdgcn_mfma_f32_16x16x32_bf16(afrag(sA, lane, kk + 0), wrec[kk + 0], a0, 0, 0, 0);
      a1 = __builtin_amdgcn_mfma_f32_16x16x32_bf16(afrag(sA, lane, kk + 1), wrec[kk + 1], a1, 0, 0, 0);
      a2 = __builtin_amdgcn_mfma_f32_16x16x32_bf16(afrag(sA, lane, kk + 2), wrec[kk + 2], a2, 0, 0, 0);
      a3 = __builtin_amdgcn_mfma_f32_16x16x32_bf16(afrag(sA, lane, kk + 3), wrec[kk + 3], a3, 0, 0, 0);
    }
    f32x4 acc = (a0 + a1) + (a2 + a3);
    f32x4 e = {0.f, 0.f, 0.f, 0.f};
    if (t + 1 < Tdim) {
#pragma unroll
      for (int kk = 0; kk < 4; ++kk)
        e = __builtin_amdgcn_mfma_f32_16x16x32_bf16(cvt8(xlo[kk], xhi[kk]), win[kk], e, 0, 0, 0);
    }
    // v(t+2) = relu(acc+b_rec) [+ ext_{t+1}]; C/D: col=lane&15, row=kgrp*4+j.
    // Overwrite of v(t) is safe: barrier B joined all waves' "peer >= t+1"
    // checks, and a peer publishing t+1 had finished staging v(t).
    {
      float s0 = acc[0] + b_rec_l, s1 = acc[1] + b_rec_l;
      float s2 = acc[2] + b_rec_l, s3 = acc[3] + b_rec_l;
      s0 = s0 > 0.f ? s0 : 0.f; s1 = s1 > 0.f ? s1 : 0.f;
      s2 = s2 > 0.f ? s2 : 0.f; s3 = s3 > 0.f ? s3 : 0.f;
      if (t + 1 < Tdim) {
        s0 += e[0] + b_in_l; s1 += e[1] + b_in_l;
        s2 += e[2] + b_in_l; s3 += e[3] + b_in_l;
      }
      sv0 = bfbits(s0); sv1 = bfbits(s1); sv2 = bfbits(s2); sv3 = bfbits(s3);
    }
    st_b16_c(nxt + (size_t)(16 * r + kgrp * 4 + 0) * Hdim + col, sv0);
    st_b16_c(nxt + (size_t)(16 * r + kgrp * 4 + 1) * Hdim + col, sv1);
    st_b16_c(nxt + (size_t)(16 * r + kgrp * 4 + 2) * Hdim + col, sv2);
    st_b16_c(nxt + (size_t)(16 * r + kgrp * 4 + 3) * Hdim + col, sv3);
    wait_vm0();
    __syncthreads();  // C: all waves' stores ack'd
    if (tid == 0) st_b32_c(myflag, (unsigned)(t + 2));  // publish v(t+2)
    const __bf16* tmp = cur; cur = nxt; nxt = (__bf16*)tmp;
  }

  // --- epilogue: stage v257 (cur == buf0), grid barrier, W_out, bcast ---
  {
    __syncthreads();
    i32x4 d0, d1, d2, d3;
    if (rem) {
      if (lane == 0) {
        while (ld_b32_c(wflag) < 257u) __builtin_amdgcn_s_sleep(1);
      }
      const __bf16* src = cur + (size_t)r * 16 * Hdim;
      d0 = ld_b128_c(src + gs0);
      d1 = ld_b128_c(src + gs1);
      d2 = ld_b128_c(src + gs2);
      d3 = ld_b128_c(src + gs3);
    }
    wait_vm0();
    if (rem) {
      *(i32x4*)(sA + lsA) = d0;
      *(i32x4*)(sA + lsB) = d1;
      *(i32x4*)(sA + lsC) = d2;
      *(i32x4*)(sA + lsD) = d3;
    }
    sAu[SELF_ADDR(0)] = sv0; sAu[SELF_ADDR(1)] = sv1;
    sAu[SELF_ADDR(2)] = sv2; sAu[SELF_ADDR(3)] = sv3;
    __syncthreads();
  }
  // one-shot grid barrier (tail-scratch safety: nobody overwrites scratch
  // with output until everyone staged its state into LDS). Proven protocol.
  if (tid == 0) st_b32_c(gflags + (size_t)wg * 16, 1u);
  if (tid < 128) {
    unsigned* f = gflags + (size_t)tid * 16;
    while (ld_b32_c(f) < 1u) __builtin_amdgcn_s_sleep(1);
  }
  __syncthreads();

  f32x4 a0 = {0.f, 0.f, 0.f, 0.f}, a1 = a0;
#pragma unroll
  for (int kk = 0; kk < 32; kk += 2) {
    const float* p0 = W_out + (size_t)col * Hdim + (kk + 0) * 32 + kgrp * 8;
    const float* p1 = W_out + (size_t)col * Hdim + (kk + 1) * 32 + kgrp * 8;
    a0 = __builtin_amdgcn_mfma_f32_16x16x32_bf16(
        afrag(sA, lane, kk + 0), cvt8(*(const f32x4*)p0, *(const f32x4*)(p0 + 4)), a0, 0, 0, 0);
    a1 = __builtin_amdgcn_mfma_f32_16x16x32_bf16(
        afrag(sA, lane, kk + 1), cvt8(*(const f32x4*)p1, *(const f32x4*)(p1 + 4)), a1, 0, 0, 0);
  }
  f32x4 acc = a0 + a1;
  float bo = b_out[col];
  __syncthreads();  // afrag reads done before sA reuse
  float* sP = (float*)sA;  // 16 x 128 plop tile (f32, 8KB), [batch row][col]
#pragma unroll
  for (int j = 0; j < 4; ++j)
    sP[(kgrp * 4 + j) * 128 + ww * 16 + (lane & 15)] = acc[j] + bo;
  __syncthreads();

  int h32 = tid & 31, tloc = tid >> 5;
  for (int b = 0; b < 16; ++b) {
    f32x4 v = *(const f32x4*)(sP + b * 128 + h32 * 4);
#pragma unroll
    for (int tb = 0; tb < 16; ++tb) {
      int t = tb * 16 + tloc;
      *(f32x4*)(out + ((size_t)(16 * r + b) * Tdim + t) * Hdim + 128 * c + h32 * 4) = v;
    }
  }
}

extern "C" void kernel_launch(void* const* d_in, const int* in_sizes, int n_in,
                              void* d_out, int out_size, void* d_ws, size_t ws_size,
                              hipStream_t stream) {
  const float* x = (const float*)d_in[0];
  const float* W_in = (const float*)d_in[1];
  const float* b_in = (const float*)d_in[2];
  const float* W_rec = (const float*)d_in[3];
  const float* b_rec = (const float*)d_in[4];
  const float* W_out = (const float*)d_in[5];
  const float* b_out = (const float*)d_in[6];
  float* out = (float*)d_out;
  (void)in_sizes; (void)n_in; (void)out_size;

  char* scratch = (ws_size >= SCRATCH_BYTES)
                      ? (char*)d_ws
                      : ((char*)d_out + OUT_BYTES - SCRATCH_BYTES);

  zero_cnt<<<dim3(CNT_BYTES / 1024), dim3(256), 0, stream>>>((unsigned*)scratch);
  rnn_fused<<<dim3(128), dim3(512), 0, stream>>>(x, W_in, b_in, W_rec, b_rec,
                                                 W_out, b_out, out, scratch);
}

// Round 12
// 1257.733 us; speedup vs baseline: 2.0376x; 1.2496x over previous
//
#include <hip/hip_runtime.h>

// RNNSequenceEncoder: B=256, T=256, IN=128, H=1024
// Round-12 = R4 (proven best, 1257us) with ONE change: cross-WG exchange ops
// use AGENT scope (sc1) instead of SYSTEM scope (sc0 sc1).
// Rationale (LLVM AMDGPUUsage gfx94x/gfx950 memory model): SC bits encode
// scope - sc0 = workgroup (explains R5/R6 deadlocks: those "XCD-local" ops
// were CU-local), sc1 = agent/device, sc0+sc1 = system. R4-R11 ran the whole
// protocol at SYSTEM scope, plausibly bypassing the memory-side Infinity
// Cache and round-tripping HBM (~0.9us legs; R10 showed time scales with CP
// volume). Agent scope stops at the device coherence point (IF$): stores
// write through L1/L2, loads bypass L1/L2 and read IF$ - correct for
// single-GPU cross-XCD exchange, and much faster if the model is right.
// Everything else is byte-identical to the 1257us R4 kernel.
//   - 128 WGs x 512 threads: row-block r (16 batch rows) x 8 WGs (128 cols)
//   - W_rec slice in VGPRs; state tile staged to LDS (XOR swizzle); ext
//     folded into state write; distributed per-WG epoch flags.

#define Bdim 256
#define Tdim 256
#define INdim 128
#define Hdim 1024

typedef __attribute__((ext_vector_type(8))) __bf16 bf16x8;
typedef __attribute__((ext_vector_type(4))) float f32x4;
typedef __attribute__((ext_vector_type(4))) int i32x4;

#define OUT_BYTES ((size_t)Bdim * Tdim * Hdim * 4)   /* 256 MB */
#define SBYTES ((size_t)Bdim * Hdim * 2)             /* one bf16 state buffer: 512 KB */
#define CNT_BYTES 32768
#define SCRATCH_BYTES (CNT_BYTES + 2 * SBYTES)

// --- device-coherent ops, AGENT scope (sc1): bypass L1+L2 to the device
// coherence point (IF$); visible to all XCDs. ---
static __device__ __forceinline__ void st_b16_c(void* p, unsigned v) {
  asm volatile("global_store_short %0, %1, off sc1" :: "v"(p), "v"(v) : "memory");
}
static __device__ __forceinline__ void st_b32_c(void* p, unsigned v) {
  asm volatile("global_store_dword %0, %1, off sc1" :: "v"(p), "v"(v) : "memory");
}
static __device__ __forceinline__ unsigned ld_b32_c(const void* p) {
  unsigned v;
  asm volatile("global_load_dword %0, %1, off sc1\n\ts_waitcnt vmcnt(0)"
               : "=v"(v) : "v"(p) : "memory");
  return v;
}
static __device__ __forceinline__ i32x4 ld_b128_c(const void* p) {
  i32x4 v;
  asm volatile("global_load_dwordx4 %0, %1, off sc1" : "=v"(v) : "v"(p) : "memory");
  return v;
}
static __device__ __forceinline__ void wait_vm0() {
  asm volatile("s_waitcnt vmcnt(0)" ::: "memory");
}

static __device__ __forceinline__ bf16x8 cvt8(f32x4 lo, f32x4 hi) {
  bf16x8 r;
  r[0] = (__bf16)lo[0]; r[1] = (__bf16)lo[1]; r[2] = (__bf16)lo[2]; r[3] = (__bf16)lo[3];
  r[4] = (__bf16)hi[0]; r[5] = (__bf16)hi[1]; r[6] = (__bf16)hi[2]; r[7] = (__bf16)hi[3];
  return r;
}

// Stage 16 rows x 1024 cols bf16 (32KB) coherence-point -> LDS, XOR swizzle on
// 16B chunks within each row (chunk ch lands at ch ^ (row&7)). 512 threads,
// 4 pipelined loads, one vmcnt(0), then LDS writes. (PROVEN R4 code.)
static __device__ __forceinline__ void stage16c(const __bf16* __restrict__ src,
                                                __bf16* sA, int tid) {
  int r0 = (tid + 0) >> 7, c0 = (tid + 0) & 127;
  int r1 = (tid + 512) >> 7, c1 = (tid + 512) & 127;
  int r2 = (tid + 1024) >> 7, c2 = (tid + 1024) & 127;
  int r3 = (tid + 1536) >> 7, c3 = (tid + 1536) & 127;
  i32x4 v0 = ld_b128_c(src + (size_t)r0 * Hdim + c0 * 8);
  i32x4 v1 = ld_b128_c(src + (size_t)r1 * Hdim + c1 * 8);
  i32x4 v2 = ld_b128_c(src + (size_t)r2 * Hdim + c2 * 8);
  i32x4 v3 = ld_b128_c(src + (size_t)r3 * Hdim + c3 * 8);
  wait_vm0();
  *(i32x4*)(sA + (size_t)r0 * Hdim + ((c0 ^ (r0 & 7)) << 3)) = v0;
  *(i32x4*)(sA + (size_t)r1 * Hdim + ((c1 ^ (r1 & 7)) << 3)) = v1;
  *(i32x4*)(sA + (size_t)r2 * Hdim + ((c2 ^ (r2 & 7)) << 3)) = v2;
  *(i32x4*)(sA + (size_t)r3 * Hdim + ((c3 ^ (r3 & 7)) << 3)) = v3;
}

// A-fragment: lane holds A[row=lane&15][k0..k0+7], k0 = kk*32 + (lane>>4)*8,
// through the same XOR swizzle. A and B use identical K-packing so any HW
// K-permutation cancels.
static __device__ __forceinline__ bf16x8 afrag(const __bf16* sA, int lane, int kk) {
  int row = lane & 15;
  int ch = kk * 4 + (lane >> 4);
  return *(const bf16x8*)(sA + (size_t)row * Hdim + ((ch ^ (row & 7)) << 3));
}

__global__ void zero_cnt(unsigned* c) { c[blockIdx.x * 256 + threadIdx.x] = 0u; }

__global__ void __launch_bounds__(512, 1)
rnn_fused(const float* __restrict__ x, const float* __restrict__ W_in,
          const float* __restrict__ b_in, const float* __restrict__ W_rec,
          const float* __restrict__ b_rec, const float* __restrict__ W_out,
          const float* __restrict__ b_out, float* __restrict__ out,
          char* __restrict__ scratch) {
  __shared__ __align__(16) __bf16 sA[16 * Hdim];  // 32 KB

  unsigned* counters = (unsigned*)scratch;
  __bf16* buf0 = (__bf16*)(scratch + CNT_BYTES);
  __bf16* buf1 = buf0 + (size_t)Bdim * Hdim;

  int wg = blockIdx.x;               // 0..127
  int idx = wg >> 3;
  int r = (wg & 7) + 8 * (idx & 1);  // row block 0..15; its 8 WGs share wg&7
  int c = idx >> 1;                  // col chunk 0..7 (128 H cols)
  int tid = threadIdx.x;
  int lane = tid & 63;
  int ww = tid >> 6;                 // wave 0..7
  int kgrp = lane >> 4;
  int col = c * 128 + ww * 16 + (lane & 15);  // H column (MFMA n = lane&15)

  // flags: row-block r's 8 flags at counters[(r*8+i)*32], 128B apart
  unsigned* rbf = counters + (size_t)r * 8 * 32;
  unsigned* myflag = rbf + (size_t)c * 32;
  unsigned* gflags = counters + 4096;  // 128 one-shot flags, 64B apart

  // --- preload weights into registers (normal cached loads; read-only) ---
  bf16x8 wrec[32];  // W_rec row `col`, K=1024 -> 128 VGPRs
#pragma unroll
  for (int kk = 0; kk < 32; ++kk) {
    const float* p = W_rec + (size_t)col * Hdim + kk * 32 + kgrp * 8;
    wrec[kk] = cvt8(*(const f32x4*)p, *(const f32x4*)(p + 4));
  }
  bf16x8 win[4];    // W_in row `col`, K=128
#pragma unroll
  for (int kk = 0; kk < 4; ++kk) {
    const float* p = W_in + (size_t)col * INdim + kk * 32 + kgrp * 8;
    win[kk] = cvt8(*(const f32x4*)p, *(const f32x4*)(p + 4));
  }
  float b_rec_l = b_rec[col];
  float b_in_l = b_in[col];

  int xrow = 16 * r + (lane & 15);
  int xk0 = kgrp * 8;

  // --- phase 0: buf0 = version 1 = ext_0 (agent-coherent stores) ---
  {
    f32x4 e = {0.f, 0.f, 0.f, 0.f};
#pragma unroll
    for (int kk = 0; kk < 4; ++kk) {
      const float* p = x + ((size_t)xrow * Tdim + 0) * INdim + kk * 32 + xk0;
      e = __builtin_amdgcn_mfma_f32_16x16x32_bf16(
          cvt8(*(const f32x4*)p, *(const f32x4*)(p + 4)), win[kk], e, 0, 0, 0);
    }
#pragma unroll
    for (int j = 0; j < 4; ++j) {
      __bf16 b = (__bf16)(e[j] + b_in_l);
      st_b16_c(buf0 + (size_t)(16 * r + kgrp * 4 + j) * Hdim + col,
               (unsigned)__builtin_bit_cast(unsigned short, b));
    }
  }
  wait_vm0();
  __syncthreads();
  if (tid == 0) st_b32_c(myflag, 1u);
  if (tid < 8) {
    unsigned* f = rbf + tid * 32;
    while (ld_b32_c(f) < 1u) __builtin_amdgcn_s_sleep(1);
  }
  __syncthreads();

  // --- scan: 256 steps; version t+1 in buf[t&1] ---
  const __bf16* cur = buf0;
  __bf16* nxt = buf1;
  for (int t = 0; t < Tdim; ++t) {
    stage16c(cur + (size_t)r * 16 * Hdim, sA, tid);
    f32x4 xlo[4], xhi[4];
    if (t + 1 < Tdim) {
#pragma unroll
      for (int kk = 0; kk < 4; ++kk) {
        const float* p = x + ((size_t)xrow * Tdim + (t + 1)) * INdim + kk * 32 + xk0;
        xlo[kk] = *(const f32x4*)p;
        xhi[kk] = *(const f32x4*)(p + 4);
      }
    }
    __syncthreads();
    f32x4 a0 = {0.f, 0.f, 0.f, 0.f}, a1 = a0, a2 = a0, a3 = a0;
#pragma unroll
    for (int kk = 0; kk < 32; kk += 4) {
      a0 = __builtin_amdgcn_mfma_f32_16x16x32_bf16(afrag(sA, lane, kk + 0), wrec[kk + 0], a0, 0, 0, 0);
      a1 = __builtin_amdgcn_mfma_f32_16x16x32_bf16(afrag(sA, lane, kk + 1), wrec[kk + 1], a1, 0, 0, 0);
      a2 = __builtin_amdgcn_mfma_f32_16x16x32_bf16(afrag(sA, lane, kk + 2), wrec[kk + 2], a2, 0, 0, 0);
      a3 = __builtin_amdgcn_mfma_f32_16x16x32_bf16(afrag(sA, lane, kk + 3), wrec[kk + 3], a3, 0, 0, 0);
    }
    f32x4 acc = (a0 + a1) + (a2 + a3);
    f32x4 e = {0.f, 0.f, 0.f, 0.f};
    if (t + 1 < Tdim) {
#pragma unroll
      for (int kk = 0; kk < 4; ++kk)
        e = __builtin_amdgcn_mfma_f32_16x16x32_bf16(cvt8(xlo[kk], xhi[kk]), win[kk], e, 0, 0, 0);
    }
    // C/D layout: col = lane&15, row = (lane>>4)*4 + j; agent-coherent stores
#pragma unroll
    for (int j = 0; j < 4; ++j) {
      float s = acc[j] + b_rec_l;
      s = s > 0.f ? s : 0.f;
      float v = (t + 1 < Tdim) ? (s + e[j] + b_in_l) : s;
      __bf16 b = (__bf16)v;
      st_b16_c(nxt + (size_t)(16 * r + kgrp * 4 + j) * Hdim + col,
               (unsigned)__builtin_bit_cast(unsigned short, b));
    }
    // publish version t+2: own stores ack'd -> barrier -> flag -> poll peers.
    // Poll exit at >= t+2 also proves nobody still reads version t+1's buffer
    // (their reads of it finished before they arrived), so 2-buffer is safe.
    unsigned tgt = (unsigned)(t + 2);
    wait_vm0();
    __syncthreads();
    if (tid == 0) st_b32_c(myflag, tgt);
    if (tid < 8) {
      unsigned* f = rbf + tid * 32;
      while (ld_b32_c(f) < tgt) __builtin_amdgcn_s_sleep(1);
    }
    __syncthreads();
    const __bf16* tmp = cur; cur = nxt; nxt = (__bf16*)tmp;
  }

  // --- output: plop = state_257 @ W_out^T + b_out, broadcast over T ---
  // version 257 is in buf0 (cur == buf0 after 256 swaps)
  stage16c(buf0 + (size_t)r * 16 * Hdim, sA, tid);
  __syncthreads();
  // one-shot grid barrier (tail-scratch safety: nobody writes output over the
  // scratch region until everyone staged its state into LDS)
  if (tid == 0) st_b32_c(gflags + (size_t)wg * 16, 1u);
  if (tid < 128) {
    unsigned* f = gflags + (size_t)tid * 16;
    while (ld_b32_c(f) < 1u) __builtin_amdgcn_s_sleep(1);
  }
  __syncthreads();

  f32x4 a0 = {0.f, 0.f, 0.f, 0.f}, a1 = a0;
#pragma unroll
  for (int kk = 0; kk < 32; kk += 2) {
    const float* p0 = W_out + (size_t)col * Hdim + (kk + 0) * 32 + kgrp * 8;
    const float* p1 = W_out + (size_t)col * Hdim + (kk + 1) * 32 + kgrp * 8;
    a0 = __builtin_amdgcn_mfma_f32_16x16x32_bf16(
        afrag(sA, lane, kk + 0), cvt8(*(const f32x4*)p0, *(const f32x4*)(p0 + 4)), a0, 0, 0, 0);
    a1 = __builtin_amdgcn_mfma_f32_16x16x32_bf16(
        afrag(sA, lane, kk + 1), cvt8(*(const f32x4*)p1, *(const f32x4*)(p1 + 4)), a1, 0, 0, 0);
  }
  f32x4 acc = a0 + a1;
  float bo = b_out[col];
  __syncthreads();  // afrag reads done before sA reuse
  float* sP = (float*)sA;  // 16 x 128 plop tile (f32, 8KB)
#pragma unroll
  for (int j = 0; j < 4; ++j)
    sP[(kgrp * 4 + j) * 128 + ww * 16 + (lane & 15)] = acc[j] + bo;
  __syncthreads();

  int h32 = tid & 31, tloc = tid >> 5;  // 32 f32x4-cols, 16 t-phases
  for (int b = 0; b < 16; ++b) {
    f32x4 v = *(const f32x4*)(sP + b * 128 + h32 * 4);
#pragma unroll
    for (int tb = 0; tb < 16; ++tb) {
      int t = tb * 16 + tloc;
      *(f32x4*)(out + ((size_t)(16 * r + b) * Tdim + t) * Hdim + 128 * c + h32 * 4) = v;
    }
  }
}

extern "C" void kernel_launch(void* const* d_in, const int* in_sizes, int n_in,
                              void* d_out, int out_size, void* d_ws, size_t ws_size,
                              hipStream_t stream) {
  const float* x = (const float*)d_in[0];
  const float* W_in = (const float*)d_in[1];
  const float* b_in = (const float*)d_in[2];
  const float* W_rec = (const float*)d_in[3];
  const float* b_rec = (const float*)d_in[4];
  const float* W_out = (const float*)d_in[5];
  const float* b_out = (const float*)d_in[6];
  float* out = (float*)d_out;
  (void)in_sizes; (void)n_in; (void)out_size;

  char* scratch = (ws_size >= SCRATCH_BYTES)
                      ? (char*)d_ws
                      : ((char*)d_out + OUT_BYTES - SCRATCH_BYTES);

  zero_cnt<<<dim3(CNT_BYTES / 1024), dim3(256), 0, stream>>>((unsigned*)scratch);
  rnn_fused<<<dim3(128), dim3(512), 0, stream>>>(x, W_in, b_in, W_rec, b_rec,
                                                 W_out, b_out, out, scratch);
}